// Round 4
// baseline (840.277 us; speedup 1.0000x reference)
//
#include <hip/hip_runtime.h>

#define TT 512
#define DD 64
#define NHC 16          // steps per LDS ring chunk
#define NCHUNK 64       // 32 encoder + 32 decoder chunks
#define BB 1024

__device__ __forceinline__ float fexp2(float x){ return __builtin_amdgcn_exp2f(x); }
__device__ __forceinline__ float frcp (float x){ return __builtin_amdgcn_rcpf(x); }

// DPP (full-rate VALU cross-lane). quad_perm with uniform selectors and
// row_ror:8 are direction/encoding-proof; row_ror:4/12 direction is resolved
// by a runtime probe (see below), never assumed.
template<int C>
__device__ __forceinline__ float dppf(float x){
  return __int_as_float(__builtin_amdgcn_update_dpp(0, __float_as_int(x), C, 0xF, 0xF, true));
}
template<int C>
__device__ __forceinline__ int dppi(int x){
  return __builtin_amdgcn_update_dpp(0, x, C, 0xF, 0xF, true);
}

template<int N> struct IC { static constexpr int v = N; };

// Block = 192: wave0 = recurrence for 4 batch elements (16 lanes each);
// waves 1,2 = layer-0 input projector, one chunk ahead, into the LDS ring.
// Ring entry per step: 128 floats = [elem 0..3][pos 0..31], where W-row
// r = gate*8 + j maps to pos = (gate*4 + (j&3))*2 + (j>>2)  (slot-pairs
// adjacent so the recurrence reads one float2 per lane).
__global__ __launch_bounds__(192) void seq2seq_kernel(
    const float* __restrict__ x,
    const float* __restrict__ h0,
    const float* __restrict__ c0,
    const float* __restrict__ eWih0, const float* __restrict__ eWihR,
    const float* __restrict__ eWhh,  const float* __restrict__ eBih, const float* __restrict__ eBhh,
    const float* __restrict__ dWih0, const float* __restrict__ dWihR,
    const float* __restrict__ dWhh,  const float* __restrict__ dBih, const float* __restrict__ dBhh,
    const float* __restrict__ linW,  const float* __restrict__ linB,
    float* __restrict__ out)
{
  __shared__ float ring[2 * NHC * 128];
  const int tid = threadIdx.x;

  if (tid < 64) {
    // ---------------- wave0: recurrence, 4 elements ----------------
    const int lane = tid;
    const int row  = lane >> 4;       // element slot within wave
    const int L    = lane & 15;
    const int u    = L >> 2;          // unit-quad index 0..3
    const int g    = L & 3;           // torch gate 0=i 1=f 2=g 3=o
    const int e    = blockIdx.x * 4 + row;

    const bool is_tanh = (g == 2);
    const float s_act = is_tanh ? 2.885390082f : 1.44269504f;
    const float a_act = is_tanh ? 2.0f : 1.0f;
    const float b_act = is_tanh ? -1.0f : 0.0f;

    // --- runtime direction probe for row_ror:4 (uniform across wave) ---
    // A[k] = ror(4k)(H) holds h_{(u + d*k)&3}; d = 1 or 3 depending on HW
    // rotate direction. Weight columns are loaded as (u + d*k)&3 to match.
    const int p4 = dppi<0x124>(u);
    const int d  = __builtin_amdgcn_readfirstlane((p4 - u) & 3);   // 1 or 3

    // state
    float H0[3], H1[3];      // h_u, h_{u+4} per layer (quad-uniform)
    float cs0[3], cs1[3];    // c_u, c_{u+4}
    float sd0[3], sd1[3];    // self-dot (+bias) feeding next step's pre
    float bd10, bd11, bd20, bd21;   // skew regs: below-dots for layers 1,2
    bd10 = bd11 = bd20 = bd21 = 0.f;

    // weights (rotated columns)
    float WSA[3][2][4], WSB[3][2][4];   // Whh
    float WBA[2][2][4], WBB[2][2][4];   // Wih_rest (below, for layers 1,2)
    float Bss[2][2];                    // biases for layers 1,2

#pragma unroll
    for (int l = 0; l < 3; ++l) {
      H0[l]  = h0[((size_t)l * BB + e) * 8 + u];
      H1[l]  = h0[((size_t)l * BB + e) * 8 + u + 4];
      cs0[l] = c0[((size_t)l * BB + e) * 8 + u];
      cs1[l] = c0[((size_t)l * BB + e) * 8 + u + 4];
    }

    float A[4], Bv[4];
    auto rot4 = [&](float a, float b) {
      A[0] = a; A[1] = dppf<0x124>(a); A[2] = dppf<0x128>(a); A[3] = dppf<0x12C>(a);
      Bv[0] = b; Bv[1] = dppf<0x124>(b); Bv[2] = dppf<0x128>(b); Bv[3] = dppf<0x12C>(b);
    };
    auto dot8r = [&](const float wa[4], const float wb[4], float base) {
      float r0 = fmaf(wa[0], A[0], base);
      float r1 = wa[1] * A[1];
      r0 = fmaf(wa[2], A[2], r0);
      r1 = fmaf(wa[3], A[3], r1);
      r0 = fmaf(wb[0], Bv[0], r0);
      r1 = fmaf(wb[1], Bv[1], r1);
      r0 = fmaf(wb[2], Bv[2], r0);
      r1 = fmaf(wb[3], Bv[3], r1);
      return r0 + r1;
    };

    auto load_phase = [&](const float* WihR, const float* Whh,
                          const float* Bih, const float* Bhh) {
#pragma unroll
      for (int l = 0; l < 3; ++l)
#pragma unroll
        for (int s = 0; s < 2; ++s) {
          const int r = l * 32 + g * 8 + u + 4 * s;
#pragma unroll
          for (int k = 0; k < 4; ++k) {
            const int col = (u + d * k) & 3;
            WSA[l][s][k] = Whh[r * 8 + col];
            WSB[l][s][k] = Whh[r * 8 + 4 + col];
          }
        }
#pragma unroll
      for (int l = 0; l < 2; ++l)
#pragma unroll
        for (int s = 0; s < 2; ++s) {
          const int r = l * 32 + g * 8 + u + 4 * s;
#pragma unroll
          for (int k = 0; k < 4; ++k) {
            const int col = (u + d * k) & 3;
            WBA[l][s][k] = WihR[r * 8 + col];
            WBB[l][s][k] = WihR[r * 8 + 4 + col];
          }
          Bss[l][s] = Bih[(l + 1) * 32 + g * 8 + u + 4 * s]
                    + Bhh[(l + 1) * 32 + g * 8 + u + 4 * s];
        }
      // self-dots from current h (layer-0 bias lives in the ring values)
#pragma unroll
      for (int l = 0; l < 3; ++l) {
        rot4(H0[l], H1[l]);
        sd0[l] = dot8r(WSA[l][0], WSB[l][0], l ? Bss[l - 1][0] : 0.f);
        sd1[l] = dot8r(WSA[l][1], WSB[l][1], l ? Bss[l - 1][1] : 0.f);
      }
    };

    // one LSTM cell step for layer l (both unit-slots); o0/o1 = below-dots
    // feeding layer l+1 on the next skewed iteration.
    auto lstep = [&](auto LC, float in0, float in1, float &o0, float &o1) {
      constexpr int l = decltype(LC)::v;
      float pre0 = in0 + sd0[l];
      float pre1 = in1 + sd1[l];
      float act0 = fmaf(a_act, frcp(1.f + fexp2(-s_act * pre0)), b_act);
      float act1 = fmaf(a_act, frcp(1.f + fexp2(-s_act * pre1)), b_act);
      // gather i,f,g,o of this quad's units: absolute quad_perm broadcasts
      float Gi0 = dppf<0x00>(act0), Gf0 = dppf<0x55>(act0);
      float Gg0 = dppf<0xAA>(act0), Go0 = dppf<0xFF>(act0);
      float Gi1 = dppf<0x00>(act1), Gf1 = dppf<0x55>(act1);
      float Gg1 = dppf<0xAA>(act1), Go1 = dppf<0xFF>(act1);
      float cn0 = fmaf(Gf0, cs0[l], Gi0 * Gg0); cs0[l] = cn0;
      float cn1 = fmaf(Gf1, cs1[l], Gi1 * Gg1); cs1[l] = cn1;
      float th0 = fmaf(2.f, frcp(1.f + fexp2(-2.885390082f * cn0)), -1.f);
      float th1 = fmaf(2.f, frcp(1.f + fexp2(-2.885390082f * cn1)), -1.f);
      float h0n = Go0 * th0;
      float h1n = Go1 * th1;
      H0[l] = h0n; H1[l] = h1n;
      rot4(h0n, h1n);
      sd0[l] = dot8r(WSA[l][0], WSB[l][0], l ? Bss[l - 1][0] : 0.f);
      sd1[l] = dot8r(WSA[l][1], WSB[l][1], l ? Bss[l - 1][1] : 0.f);
      if constexpr (l < 2) {
        o0 = dot8r(WBA[l][0], WBB[l][0], 0.f);
        o1 = dot8r(WBA[l][1], WBB[l][1], 0.f);
      } else {
        o0 = 0.f; o1 = 0.f;
      }
    };

    const int myoff = row * 32 + (g * 4 + u) * 2;

    auto run_chunk = [&](auto PEELED, const float* buf) {
      constexpr bool PE = (decltype(PEELED)::v != 0);
      float2 pcv = *(const float2*)(buf + myoff);
#pragma unroll 1
      for (int i = 0; i < NHC; ++i) {
        float2 pcn = *(const float2*)(buf + ((i + 1) & (NHC - 1)) * 128 + myoff);
        float n10, n11, n20, n21, z0, z1;
        lstep(IC<0>{}, pcv.x, pcv.y, n10, n11);
        n20 = 0.f; n21 = 0.f;
        if (!PE || i >= 1) lstep(IC<1>{}, bd10, bd11, n20, n21);
        if (!PE || i >= 2) lstep(IC<2>{}, bd20, bd21, z0, z1);
        bd10 = n10; bd11 = n11; bd20 = n20; bd21 = n21;
        pcv = pcn;
      }
    };

    load_phase(eWihR, eWhh, eBih, eBhh);
    __syncthreads();                    // chunk 0 ready

#pragma unroll 1
    for (int ph = 0; ph < 2; ++ph) {
      if (ph == 1) load_phase(dWihR, dWhh, dBih, dBhh);
      run_chunk(IC<1>{}, ring + ((ph * 32) & 1) * (NHC * 128));
      __syncthreads();
#pragma unroll 1
      for (int cc = 1; cc < 32; ++cc) {
        run_chunk(IC<0>{}, ring + ((ph * 32 + cc) & 1) * (NHC * 128));
        __syncthreads();
      }
      // drain the skew: layer1 t=511, layer2 t=510, layer2 t=511
      float d0, d1, z0, z1;
      lstep(IC<1>{}, bd10, bd11, d0, d1);
      lstep(IC<2>{}, bd20, bd21, z0, z1);
      lstep(IC<2>{}, d0, d1, z0, z1);
    }

    // epilogue: linear on final decoder layer-2 h
    float lwA[4], lwB[4];
#pragma unroll
    for (int k = 0; k < 4; ++k) {
      const int col = (u + d * k) & 3;
      lwA[k] = linW[col];
      lwB[k] = linW[4 + col];
    }
    rot4(H0[2], H1[2]);
    float pred = dot8r(lwA, lwB, linB[0]);
    if (L == 0) out[e] = pred;

  } else {
    // ---------------- waves 1,2: layer-0 input projectors ----------------
    const int p    = tid - 64;          // 0..127
    const int elem = p >> 5;            // 0..3
    const int wrow = p & 31;            // W-row = gate*8 + j
    const int e    = blockIdx.x * 4 + elem;
    const int gate = wrow >> 3;
    const int j    = wrow & 7;
    const int pos  = (gate * 4 + (j & 3)) * 2 + (j >> 2);
    float Wx[64];
    float b0v;

    auto load_wx = [&](const float* Wih0, const float* Bih, const float* Bhh) {
#pragma unroll
      for (int k = 0; k < 16; ++k) {
        float4 wq = *(const float4*)(Wih0 + wrow * 64 + k * 4);
        Wx[k * 4 + 0] = wq.x; Wx[k * 4 + 1] = wq.y;
        Wx[k * 4 + 2] = wq.z; Wx[k * 4 + 3] = wq.w;
      }
      b0v = Bih[wrow] + Bhh[wrow];
    };

    auto fill = [&](int fc) {
      const int tb = (fc & 31) * NHC;
      float* dst = ring + (fc & 1) * (NHC * 128) + elem * 32 + pos;
      const float* xr = x + ((size_t)e * TT + tb) * DD;
#pragma unroll 1
      for (int i = 0; i < NHC; ++i) {
        float a0 = b0v, a1 = 0.f, a2 = 0.f, a3 = 0.f;
#pragma unroll
        for (int kc = 0; kc < 16; ++kc) {
          float4 xq = *(const float4*)(xr + kc * 4);
          a0 = fmaf(Wx[kc * 4 + 0], xq.x, a0);
          a1 = fmaf(Wx[kc * 4 + 1], xq.y, a1);
          a2 = fmaf(Wx[kc * 4 + 2], xq.z, a2);
          a3 = fmaf(Wx[kc * 4 + 3], xq.w, a3);
        }
        dst[i * 128] = (a0 + a1) + (a2 + a3);
        xr += DD;
      }
    };

    load_wx(eWih0, eBih, eBhh);
    fill(0);
    __syncthreads();
#pragma unroll 1
    for (int cc = 0; cc < NCHUNK; ++cc) {
      int fc = cc + 1;
      if (fc < NCHUNK) {
        if (fc == 32) load_wx(dWih0, dBih, dBhh);
        fill(fc);
      }
      __syncthreads();
    }
  }
}

extern "C" void kernel_launch(void* const* d_in, const int* in_sizes, int n_in,
                              void* d_out, int out_size, void* d_ws, size_t ws_size,
                              hipStream_t stream) {
  const float* x     = (const float*)d_in[0];
  const float* h0    = (const float*)d_in[1];
  const float* c0    = (const float*)d_in[2];
  const float* eWih0 = (const float*)d_in[3];
  const float* eWihR = (const float*)d_in[4];
  const float* eWhh  = (const float*)d_in[5];
  const float* eBih  = (const float*)d_in[6];
  const float* eBhh  = (const float*)d_in[7];
  const float* dWih0 = (const float*)d_in[8];
  const float* dWihR = (const float*)d_in[9];
  const float* dWhh  = (const float*)d_in[10];
  const float* dBih  = (const float*)d_in[11];
  const float* dBhh  = (const float*)d_in[12];
  const float* linW  = (const float*)d_in[13];
  const float* linB  = (const float*)d_in[14];
  float* out = (float*)d_out;

  seq2seq_kernel<<<BB / 4, 192, 0, stream>>>(
      x, h0, c0, eWih0, eWihR, eWhh, eBih, eBhh,
      dWih0, dWihR, dWhh, dBih, dBhh, linW, linB, out);
}